// Round 2
// baseline (1002.243 us; speedup 1.0000x reference)
//
#include <hip/hip_runtime.h>

// All tensors are float32 buffers (values bf16-quantized by the dataset).
//
// ws layout: [0..63] gmax as uint bit patterns of floats (all values >= 0,
// so uint atomicMax == float max).

__global__ __launch_bounds__(64) void prep_kernel(unsigned int* __restrict__ gmax)
{
    gmax[threadIdx.x & 63] = 0u;
}

// ---------- encoder: per-point MLP 2->16->32->64, global channel max ----------
__global__ __launch_bounds__(256) void encoder_kernel(
    const float* __restrict__ x,   // [3 + 2N]
    const float* __restrict__ W1, const float* __restrict__ B1,   // (16,2),(16,)
    const float* __restrict__ W2, const float* __restrict__ B2,   // (32,16),(32,)
    const float* __restrict__ W3, const float* __restrict__ B3,   // (64,32),(64,)
    unsigned int* __restrict__ gmax,
    int N)
{
    float vmax[64];
#pragma unroll
    for (int c = 0; c < 64; c++) vmax[c] = 0.0f;   // ReLU outputs >= 0

    const int stride = gridDim.x * blockDim.x;
    for (int p = blockIdx.x * blockDim.x + threadIdx.x; p < N; p += stride) {
        float px = x[3 + p];
        float py = x[3 + N + p];

        float h1[16];
#pragma unroll
        for (int c = 0; c < 16; c++) {
            float v = fmaf(W1[2 * c], px, fmaf(W1[2 * c + 1], py, B1[c]));
            h1[c] = fmaxf(v, 0.0f);
        }
        float h2[32];
#pragma unroll
        for (int c = 0; c < 32; c++) {
            float a = B2[c];
#pragma unroll
            for (int k = 0; k < 16; k++) a = fmaf(W2[c * 16 + k], h1[k], a);
            h2[c] = fmaxf(a, 0.0f);
        }
#pragma unroll
        for (int c = 0; c < 64; c++) {
            float a = B3[c];
#pragma unroll
            for (int k = 0; k < 32; k++) a = fmaf(W3[c * 32 + k], h2[k], a);
            a = fmaxf(a, 0.0f);
            vmax[c] = fmaxf(vmax[c], a);
        }
    }

    // wave butterfly reduction (64 lanes)
#pragma unroll
    for (int c = 0; c < 64; c++) {
        float v = vmax[c];
#pragma unroll
        for (int off = 32; off > 0; off >>= 1) {
            float o = __shfl_xor(v, off, 64);
            v = fmaxf(v, o);
        }
        vmax[c] = v;
    }

    __shared__ float wred[4 * 64];
    int wid = threadIdx.x >> 6;
    int lane = threadIdx.x & 63;
    if (lane == 0) {
#pragma unroll
        for (int c = 0; c < 64; c++) wred[wid * 64 + c] = vmax[c];
    }
    __syncthreads();
    if (threadIdx.x < 64) {
        float m = wred[threadIdx.x];
        m = fmaxf(m, wred[64 + threadIdx.x]);
        m = fmaxf(m, wred[128 + threadIdx.x]);
        m = fmaxf(m, wred[192 + threadIdx.x]);
        atomicMax(gmax + threadIdx.x, __float_as_uint(m)); // valid: all >= 0
    }
}

// ---------- tail: everything after feat, one block ----------
__global__ __launch_bounds__(256) void tail_kernel(
    const float* __restrict__ x,
    const float* __restrict__ hx,  const float* __restrict__ cx,
    const float* __restrict__ fcw, const float* __restrict__ fcb,
    const float* __restrict__ o1w, const float* __restrict__ o1b,
    const float* __restrict__ o2w, const float* __restrict__ o2b,
    const float* __restrict__ pw,  const float* __restrict__ pb,
    const float* __restrict__ wih, const float* __restrict__ whh,
    const float* __restrict__ bih, const float* __restrict__ bhh,
    const float* __restrict__ q1w, const float* __restrict__ q1b,
    const float* __restrict__ q2w, const float* __restrict__ q2b,
    const float* __restrict__ aw1, const float* __restrict__ ab1,
    const float* __restrict__ aw2, const float* __restrict__ ab2,
    const float* __restrict__ ciw1, const float* __restrict__ cib1,
    const float* __restrict__ ciw2, const float* __restrict__ cib2,
    const float* __restrict__ cew1, const float* __restrict__ ceb1,
    const float* __restrict__ cew2, const float* __restrict__ ceb2,
    const unsigned int* __restrict__ gmax,
    float* __restrict__ out)
{
    __shared__ float feat[64], obs[64], sig8[8], pose[8], z[128], hnew[128];
    __shared__ float zp1s[64], zp2s[64], a1s[16], cih[16], ceh[16], logits[5];
    __shared__ float odom[3];
    int t = threadIdx.x;

    if (t < 64) feat[t] = __uint_as_float(gmax[t]);
    if (t < 3)  odom[t] = x[t];
    __syncthreads();

    if (t < 64) {                       // obs = fcw @ feat + fcb
        float a = fcb[t];
        for (int k = 0; k < 64; k++) a = fmaf(fcw[t * 64 + k], feat[k], a);
        obs[t] = a;
    } else if (t < 72) {                // sig8 = sigmoid(o1w @ odom + o1b)
        int r = t - 64;
        float a = o1b[r];
        for (int k = 0; k < 3; k++) a = fmaf(o1w[r * 3 + k], odom[k], a);
        sig8[r] = 1.0f / (1.0f + expf(-a));
    }
    __syncthreads();

    if (t < 8) {                        // pose = relu(o2w @ sig8 + o2b)
        float a = o2b[t];
        for (int k = 0; k < 8; k++) a = fmaf(o2w[t * 8 + k], sig8[k], a);
        pose[t] = fmaxf(a, 0.0f);
    }
    __syncthreads();

    if (t < 128) {                      // z = relu(pw @ [obs;pose] + pb)
        float a = pb[t];
        for (int k = 0; k < 64; k++) a = fmaf(pw[t * 72 + k], obs[k], a);
        for (int k = 0; k < 8; k++)  a = fmaf(pw[t * 72 + 64 + k], pose[k], a);
        z[t] = fmaxf(a, 0.0f);
    }
    __syncthreads();

    if (t < 128) {                      // LSTM cell
        float g[4];
#pragma unroll
        for (int j = 0; j < 4; j++) {
            int r = j * 128 + t;
            float a = bih[r] + bhh[r];
            for (int k = 0; k < 128; k++) a = fmaf(wih[r * 128 + k], z[k], a);
            for (int k = 0; k < 128; k++) a = fmaf(whh[r * 128 + k], hx[k], a);
            g[j] = a;
        }
        float ig = 1.0f / (1.0f + expf(-g[0]));
        float fg = 1.0f / (1.0f + expf(-g[1]));
        float gg = tanhf(g[2]);
        float og = 1.0f / (1.0f + expf(-g[3]));
        float cn = fg * cx[t] + ig * gg;
        float hn = og * tanhf(cn);
        hnew[t] = hn;
        out[7 + t]   = hn;              // hx2
        out[135 + t] = cn;              // cx2
    }
    __syncthreads();

    if (t < 64) {                       // zp1 = relu(q1w @ h_new + q1b)
        float a = q1b[t];
        for (int k = 0; k < 128; k++) a = fmaf(q1w[t * 128 + k], hnew[k], a);
        zp1s[t] = fmaxf(a, 0.0f);
    }
    __syncthreads();

    if (t < 64) {                       // zp2 = relu(q2w @ zp1 + q2b)
        float a = q2b[t];
        for (int k = 0; k < 64; k++) a = fmaf(q2w[t * 64 + k], zp1s[k], a);
        zp2s[t] = fmaxf(a, 0.0f);
    }
    __syncthreads();

    if (t < 16) {
        float a = ab1[t];
        for (int k = 0; k < 64; k++) a = fmaf(aw1[t * 64 + k], zp2s[k], a);
        a1s[t] = fmaxf(a, 0.0f);
    } else if (t < 32) {
        int r = t - 16;
        float a = cib1[r];
        for (int k = 0; k < 64; k++) a = fmaf(ciw1[r * 64 + k], zp2s[k], a);
        cih[r] = fmaxf(a, 0.0f);
    } else if (t < 48) {
        int r = t - 32;
        float a = ceb1[r];
        for (int k = 0; k < 64; k++) a = fmaf(cew1[r * 64 + k], zp2s[k], a);
        ceh[r] = fmaxf(a, 0.0f);
    }
    __syncthreads();

    if (t < 5) {
        float a = ab2[t];
        for (int k = 0; k < 16; k++) a = fmaf(aw2[t * 16 + k], a1s[k], a);
        logits[t] = a;
    } else if (t == 5) {                // ci
        float a = cib2[0];
        for (int k = 0; k < 16; k++) a = fmaf(ciw2[k], cih[k], a);
        out[5] = a;
    } else if (t == 6) {                // ce  (bias fixed: ceb2, was cew2)
        float a = ceb2[0];
        for (int k = 0; k < 16; k++) a = fmaf(cew2[k], ceh[k], a);
        out[6] = a;
    }
    if (t >= 8 && t < 16) out[263 + (t - 8)] = pose[t - 8];  // pose
    __syncthreads();

    if (t == 0) {                       // softmax over 5 logits
        float m = logits[0];
        for (int i = 1; i < 5; i++) m = fmaxf(m, logits[i]);
        float e[5], s = 0.0f;
        for (int i = 0; i < 5; i++) { e[i] = expf(logits[i] - m); s += e[i]; }
        for (int i = 0; i < 5; i++) out[i] = e[i] / s;
    }
}

extern "C" void kernel_launch(void* const* d_in, const int* in_sizes, int n_in,
                              void* d_out, int out_size, void* d_ws, size_t ws_size,
                              hipStream_t stream)
{
    const float* x    = (const float*)d_in[0];
    const float* hx   = (const float*)d_in[1];
    const float* cx   = (const float*)d_in[2];
    const float* c1w  = (const float*)d_in[3];
    const float* c1b  = (const float*)d_in[4];
    const float* c2w  = (const float*)d_in[5];
    const float* c2b  = (const float*)d_in[6];
    const float* c3w  = (const float*)d_in[7];
    const float* c3b  = (const float*)d_in[8];
    const float* fcw  = (const float*)d_in[9];
    const float* fcb  = (const float*)d_in[10];
    const float* o1w  = (const float*)d_in[11];
    const float* o1b  = (const float*)d_in[12];
    const float* o2w  = (const float*)d_in[13];
    const float* o2b  = (const float*)d_in[14];
    const float* pw   = (const float*)d_in[15];
    const float* pb   = (const float*)d_in[16];
    const float* wih  = (const float*)d_in[17];
    const float* whh  = (const float*)d_in[18];
    const float* bih  = (const float*)d_in[19];
    const float* bhh  = (const float*)d_in[20];
    const float* q1w  = (const float*)d_in[21];
    const float* q1b  = (const float*)d_in[22];
    const float* q2w  = (const float*)d_in[23];
    const float* q2b  = (const float*)d_in[24];
    const float* aw1  = (const float*)d_in[25];
    const float* ab1  = (const float*)d_in[26];
    const float* aw2  = (const float*)d_in[27];
    const float* ab2  = (const float*)d_in[28];
    const float* ciw1 = (const float*)d_in[29];
    const float* cib1 = (const float*)d_in[30];
    const float* ciw2 = (const float*)d_in[31];
    const float* cib2 = (const float*)d_in[32];
    const float* cew1 = (const float*)d_in[33];
    const float* ceb1 = (const float*)d_in[34];
    const float* cew2 = (const float*)d_in[35];
    const float* ceb2 = (const float*)d_in[36];

    int N = (in_sizes[0] - 3) / 2;
    unsigned int* gmax = (unsigned int*)d_ws;

    prep_kernel<<<1, 64, 0, stream>>>(gmax);
    encoder_kernel<<<512, 256, 0, stream>>>(x, c1w, c1b, c2w, c2b, c3w, c3b, gmax, N);
    tail_kernel<<<1, 256, 0, stream>>>(x, hx, cx, fcw, fcb, o1w, o1b, o2w, o2b,
                                       pw, pb, wih, whh, bih, bhh, q1w, q1b,
                                       q2w, q2b, aw1, ab1, aw2, ab2, ciw1, cib1,
                                       ciw2, cib2, cew1, ceb1, cew2, ceb2,
                                       gmax, (float*)d_out);
}

// Round 3
// 317.422 us; speedup vs baseline: 3.1575x; 3.1575x over previous
//
#include <hip/hip_runtime.h>

#define NB 512   // encoder grid; partials need NB*64*4 = 128 KB of ws

// ---------------- atomic-mode prologue (only if ws too small) ----------------
__global__ __launch_bounds__(64) void prep_kernel(unsigned int* __restrict__ g)
{
    g[threadIdx.x & 63] = 0u;
}

// ---------- encoder: per-point MLP 2->16->32->64, channel max ----------
// Weights staged in LDS; reads are wave-broadcast ds_read_b128 (no conflicts).
__global__ __launch_bounds__(256) void encoder_kernel(
    const float* __restrict__ x,   // [3 + 2N]
    const float* __restrict__ c1w, const float* __restrict__ c1b,
    const float* __restrict__ c2w, const float* __restrict__ c2b,
    const float* __restrict__ c3w, const float* __restrict__ c3b,
    float* __restrict__ ws, int N, int use_atomic)
{
    __shared__ __align__(16) float sW2[512];    // 32x16
    __shared__ __align__(16) float sW3[2048];   // 64x32
    __shared__ float sW1[32], sB1[16], sB2[32], sB3[64];
    __shared__ float wred[4 * 64];
    int t = threadIdx.x;

    if (t < 32) sW1[t] = c1w[t];
    if (t < 16) sB1[t] = c1b[t];
    if (t < 32) sB2[t] = c2b[t];
    if (t < 64) sB3[t] = c3b[t];
    for (int i = t; i < 512; i += 256)  sW2[i] = c2w[i];
    for (int i = t; i < 2048; i += 256) sW3[i] = c3w[i];
    __syncthreads();

    const float4* __restrict__ W2v = (const float4*)sW2;
    const float4* __restrict__ W3v = (const float4*)sW3;

    float vmax[64];
#pragma unroll
    for (int c = 0; c < 64; c++) vmax[c] = 0.0f;   // ReLU outputs >= 0

    const int stride = gridDim.x * blockDim.x;
    for (int p = blockIdx.x * blockDim.x + t; p < N; p += stride) {
        float px = x[3 + p];
        float py = x[3 + N + p];

        float h1[16];
#pragma unroll
        for (int c = 0; c < 16; c++)
            h1[c] = fmaxf(fmaf(sW1[2 * c], px, fmaf(sW1[2 * c + 1], py, sB1[c])), 0.0f);

        float h2[32];
#pragma unroll
        for (int c = 0; c < 32; c++) {
            float a = sB2[c];
#pragma unroll
            for (int q = 0; q < 4; q++) {
                float4 w = W2v[c * 4 + q];
                a = fmaf(w.x, h1[4 * q],
                    fmaf(w.y, h1[4 * q + 1],
                    fmaf(w.z, h1[4 * q + 2],
                    fmaf(w.w, h1[4 * q + 3], a))));
            }
            h2[c] = fmaxf(a, 0.0f);
        }

#pragma unroll 8
        for (int c = 0; c < 64; c++) {
            float a = sB3[c];
#pragma unroll
            for (int q = 0; q < 8; q++) {
                float4 w = W3v[c * 8 + q];
                a = fmaf(w.x, h2[4 * q],
                    fmaf(w.y, h2[4 * q + 1],
                    fmaf(w.z, h2[4 * q + 2],
                    fmaf(w.w, h2[4 * q + 3], a))));
            }
            // relu folded into running max (vmax >= 0 always)
            vmax[c] = fmaxf(vmax[c], a);
        }
    }

    // wave butterfly (64 lanes)
#pragma unroll
    for (int c = 0; c < 64; c++) {
        float v = vmax[c];
#pragma unroll
        for (int off = 32; off > 0; off >>= 1)
            v = fmaxf(v, __shfl_xor(v, off, 64));
        vmax[c] = v;
    }

    int wid = t >> 6, lane = t & 63;
    if (lane == 0) {
#pragma unroll
        for (int c = 0; c < 64; c++) wred[wid * 64 + c] = vmax[c];
    }
    __syncthreads();
    if (t < 64) {
        float m = fmaxf(fmaxf(wred[t], wred[64 + t]),
                        fmaxf(wred[128 + t], wred[192 + t]));
        if (use_atomic)
            atomicMax((unsigned int*)ws + t, __float_as_uint(m)); // valid: m >= 0
        else
            ws[blockIdx.x * 64 + t] = m;
    }
}

// ---------- tail: feat reduce + everything after, one 1024-thread block ----------
__global__ __launch_bounds__(1024) void tail_kernel(
    const float* __restrict__ x,
    const float* __restrict__ hx,  const float* __restrict__ cx,
    const float* __restrict__ fcw, const float* __restrict__ fcb,
    const float* __restrict__ o1w, const float* __restrict__ o1b,
    const float* __restrict__ o2w, const float* __restrict__ o2b,
    const float* __restrict__ pw,  const float* __restrict__ pb,
    const float* __restrict__ wih, const float* __restrict__ whh,
    const float* __restrict__ bih, const float* __restrict__ bhh,
    const float* __restrict__ q1w, const float* __restrict__ q1b,
    const float* __restrict__ q2w, const float* __restrict__ q2b,
    const float* __restrict__ aw1, const float* __restrict__ ab1,
    const float* __restrict__ aw2, const float* __restrict__ ab2,
    const float* __restrict__ ciw1, const float* __restrict__ cib1,
    const float* __restrict__ ciw2, const float* __restrict__ cib2,
    const float* __restrict__ cew1, const float* __restrict__ ceb1,
    const float* __restrict__ cew2, const float* __restrict__ ceb2,
    const float* __restrict__ ws, int nb, int use_atomic,
    float* __restrict__ out)
{
    __shared__ float feat[64], obs[64], sig8[8], pose[8], z[128], hnew[128];
    __shared__ float zp1s[64], zp2s[64], a1s[16], cih[16], ceh[16], logits[5];
    __shared__ float odom[3], wred2[256], gpart[1024], shx[128];
    int t = threadIdx.x;

    if (t < 3)   odom[t] = x[t];
    if (t < 128) shx[t] = hx[t];
    // reduce per-block partials (or read atomic gmax)
    if (t < 256) {
        int c = t & 63, g = t >> 6;
        float m = 0.0f;
        if (use_atomic) {
            if (g == 0) m = __uint_as_float(((const unsigned int*)ws)[c]);
        } else {
            for (int i = g; i < nb; i += 4) m = fmaxf(m, ws[i * 64 + c]);
        }
        wred2[t] = m;
    }
    __syncthreads();
    if (t < 64)
        feat[t] = fmaxf(fmaxf(wred2[t], wred2[64 + t]),
                        fmaxf(wred2[128 + t], wred2[192 + t]));
    __syncthreads();

    if (t < 64) {                       // obs = fcw @ feat + fcb
        float a = fcb[t];
        for (int k = 0; k < 64; k++) a = fmaf(fcw[t * 64 + k], feat[k], a);
        obs[t] = a;
    } else if (t < 72) {                // sig8 = sigmoid(o1w @ odom + o1b)
        int r = t - 64;
        float a = o1b[r];
        for (int k = 0; k < 3; k++) a = fmaf(o1w[r * 3 + k], odom[k], a);
        sig8[r] = 1.0f / (1.0f + expf(-a));
    }
    __syncthreads();

    if (t < 8) {                        // pose = relu(o2w @ sig8 + o2b)
        float a = o2b[t];
        for (int k = 0; k < 8; k++) a = fmaf(o2w[t * 8 + k], sig8[k], a);
        pose[t] = fmaxf(a, 0.0f);
    }
    __syncthreads();

    if (t < 128) {                      // z = relu(pw @ [obs;pose] + pb)
        float a = pb[t];
        for (int k = 0; k < 64; k++) a = fmaf(pw[t * 72 + k], obs[k], a);
        for (int k = 0; k < 8; k++)  a = fmaf(pw[t * 72 + 64 + k], pose[k], a);
        z[t] = fmaxf(a, 0.0f);
    }
    __syncthreads();

    // LSTM gate partials: t<512 -> wih row t against z; t>=512 -> whh row against shx
    {
        int r = t & 511, half = t >> 9;
        float a;
        if (half == 0) {
            a = bih[r];
            const float4* w4 = (const float4*)(wih + (size_t)r * 128);
#pragma unroll 8
            for (int q = 0; q < 32; q++) {
                float4 w = w4[q];
                a = fmaf(w.x, z[4 * q], fmaf(w.y, z[4 * q + 1],
                    fmaf(w.z, z[4 * q + 2], fmaf(w.w, z[4 * q + 3], a))));
            }
        } else {
            a = bhh[r];
            const float4* w4 = (const float4*)(whh + (size_t)r * 128);
#pragma unroll 8
            for (int q = 0; q < 32; q++) {
                float4 w = w4[q];
                a = fmaf(w.x, shx[4 * q], fmaf(w.y, shx[4 * q + 1],
                    fmaf(w.z, shx[4 * q + 2], fmaf(w.w, shx[4 * q + 3], a))));
            }
        }
        gpart[t] = a;
    }
    __syncthreads();

    if (t < 128) {                      // LSTM cell update
        float gI = gpart[t]       + gpart[512 + t];
        float gF = gpart[128 + t] + gpart[640 + t];
        float gG = gpart[256 + t] + gpart[768 + t];
        float gO = gpart[384 + t] + gpart[896 + t];
        float ig = 1.0f / (1.0f + expf(-gI));
        float fg = 1.0f / (1.0f + expf(-gF));
        float gg = tanhf(gG);
        float og = 1.0f / (1.0f + expf(-gO));
        float cn = fg * cx[t] + ig * gg;
        float hn = og * tanhf(cn);
        hnew[t] = hn;
        out[7 + t]   = hn;              // hx2
        out[135 + t] = cn;              // cx2
    }
    __syncthreads();

    if (t < 64) {                       // zp1 = relu(q1w @ h_new + q1b)
        float a = q1b[t];
        const float4* w4 = (const float4*)(q1w + (size_t)t * 128);
        for (int q = 0; q < 32; q++) {
            float4 w = w4[q];
            a = fmaf(w.x, hnew[4 * q], fmaf(w.y, hnew[4 * q + 1],
                fmaf(w.z, hnew[4 * q + 2], fmaf(w.w, hnew[4 * q + 3], a))));
        }
        zp1s[t] = fmaxf(a, 0.0f);
    }
    __syncthreads();

    if (t < 64) {                       // zp2 = relu(q2w @ zp1 + q2b)
        float a = q2b[t];
        for (int k = 0; k < 64; k++) a = fmaf(q2w[t * 64 + k], zp1s[k], a);
        zp2s[t] = fmaxf(a, 0.0f);
    }
    __syncthreads();

    if (t < 16) {
        float a = ab1[t];
        for (int k = 0; k < 64; k++) a = fmaf(aw1[t * 64 + k], zp2s[k], a);
        a1s[t] = fmaxf(a, 0.0f);
    } else if (t < 32) {
        int r = t - 16;
        float a = cib1[r];
        for (int k = 0; k < 64; k++) a = fmaf(ciw1[r * 64 + k], zp2s[k], a);
        cih[r] = fmaxf(a, 0.0f);
    } else if (t < 48) {
        int r = t - 32;
        float a = ceb1[r];
        for (int k = 0; k < 64; k++) a = fmaf(cew1[r * 64 + k], zp2s[k], a);
        ceh[r] = fmaxf(a, 0.0f);
    }
    __syncthreads();

    if (t < 5) {
        float a = ab2[t];
        for (int k = 0; k < 16; k++) a = fmaf(aw2[t * 16 + k], a1s[k], a);
        logits[t] = a;
    } else if (t == 5) {                // ci
        float a = cib2[0];
        for (int k = 0; k < 16; k++) a = fmaf(ciw2[k], cih[k], a);
        out[5] = a;
    } else if (t == 6) {                // ce
        float a = ceb2[0];
        for (int k = 0; k < 16; k++) a = fmaf(cew2[k], ceh[k], a);
        out[6] = a;
    }
    if (t >= 8 && t < 16) out[263 + (t - 8)] = pose[t - 8];  // pose
    __syncthreads();

    if (t == 0) {                       // softmax over 5 logits
        float m = logits[0];
        for (int i = 1; i < 5; i++) m = fmaxf(m, logits[i]);
        float e[5], s = 0.0f;
        for (int i = 0; i < 5; i++) { e[i] = expf(logits[i] - m); s += e[i]; }
        for (int i = 0; i < 5; i++) out[i] = e[i] / s;
    }
}

extern "C" void kernel_launch(void* const* d_in, const int* in_sizes, int n_in,
                              void* d_out, int out_size, void* d_ws, size_t ws_size,
                              hipStream_t stream)
{
    const float* x    = (const float*)d_in[0];
    const float* hx   = (const float*)d_in[1];
    const float* cx   = (const float*)d_in[2];
    const float* c1w  = (const float*)d_in[3];
    const float* c1b  = (const float*)d_in[4];
    const float* c2w  = (const float*)d_in[5];
    const float* c2b  = (const float*)d_in[6];
    const float* c3w  = (const float*)d_in[7];
    const float* c3b  = (const float*)d_in[8];
    const float* fcw  = (const float*)d_in[9];
    const float* fcb  = (const float*)d_in[10];
    const float* o1w  = (const float*)d_in[11];
    const float* o1b  = (const float*)d_in[12];
    const float* o2w  = (const float*)d_in[13];
    const float* o2b  = (const float*)d_in[14];
    const float* pw   = (const float*)d_in[15];
    const float* pb   = (const float*)d_in[16];
    const float* wih  = (const float*)d_in[17];
    const float* whh  = (const float*)d_in[18];
    const float* bih  = (const float*)d_in[19];
    const float* bhh  = (const float*)d_in[20];
    const float* q1w  = (const float*)d_in[21];
    const float* q1b  = (const float*)d_in[22];
    const float* q2w  = (const float*)d_in[23];
    const float* q2b  = (const float*)d_in[24];
    const float* aw1  = (const float*)d_in[25];
    const float* ab1  = (const float*)d_in[26];
    const float* aw2  = (const float*)d_in[27];
    const float* ab2  = (const float*)d_in[28];
    const float* ciw1 = (const float*)d_in[29];
    const float* cib1 = (const float*)d_in[30];
    const float* ciw2 = (const float*)d_in[31];
    const float* cib2 = (const float*)d_in[32];
    const float* cew1 = (const float*)d_in[33];
    const float* ceb1 = (const float*)d_in[34];
    const float* cew2 = (const float*)d_in[35];
    const float* ceb2 = (const float*)d_in[36];

    int N = (in_sizes[0] - 3) / 2;
    int use_atomic = (ws_size < (size_t)(NB * 64 * 4)) ? 1 : 0;

    if (use_atomic)
        prep_kernel<<<1, 64, 0, stream>>>((unsigned int*)d_ws);
    encoder_kernel<<<NB, 256, 0, stream>>>(x, c1w, c1b, c2w, c2b, c3w, c3b,
                                           (float*)d_ws, N, use_atomic);
    tail_kernel<<<1, 1024, 0, stream>>>(x, hx, cx, fcw, fcb, o1w, o1b, o2w, o2b,
                                        pw, pb, wih, whh, bih, bhh, q1w, q1b,
                                        q2w, q2b, aw1, ab1, aw2, ab2, ciw1, cib1,
                                        ciw2, cib2, cew1, ceb1, cew2, ceb2,
                                        (const float*)d_ws, NB, use_atomic,
                                        (float*)d_out);
}

// Round 4
// 271.004 us; speedup vs baseline: 3.6983x; 1.1713x over previous
//
#include <hip/hip_runtime.h>

#define NB 512   // encoder grid; partials need NB*64*4 = 128 KB of ws

// ---------------- atomic-mode prologue (only if ws too small) ----------------
__global__ __launch_bounds__(64) void prep_kernel(unsigned int* __restrict__ g)
{
    g[threadIdx.x & 63] = 0u;
}

// ---------- encoder: per-point MLP 2->16->32->64, channel max ----------
// Weights staged in LDS; reads are wave-broadcast ds_read_b128 (no conflicts).
// Unroll pragmas chosen to keep live VGPRs ~ vmax(64)+h2(32)+weights(<=64):
// R3 post-mortem: unroll 8 on layer 3 spilled (WRITE_SIZE 68 MB, VALUBusy 25%).
__global__ __launch_bounds__(256, 2) void encoder_kernel(
    const float* __restrict__ x,   // [3 + 2N]
    const float* __restrict__ c1w, const float* __restrict__ c1b,
    const float* __restrict__ c2w, const float* __restrict__ c2b,
    const float* __restrict__ c3w, const float* __restrict__ c3b,
    float* __restrict__ ws, int N, int use_atomic)
{
    __shared__ __align__(16) float sW2[512];    // 32x16
    __shared__ __align__(16) float sW3[2048];   // 64x32
    __shared__ float sW1[32], sB1[16], sB2[32], sB3[64];
    __shared__ float wred[4 * 64];
    int t = threadIdx.x;

    if (t < 32) sW1[t] = c1w[t];
    if (t < 16) sB1[t] = c1b[t];
    if (t < 32) sB2[t] = c2b[t];
    if (t < 64) sB3[t] = c3b[t];
    for (int i = t; i < 512; i += 256)  sW2[i] = c2w[i];
    for (int i = t; i < 2048; i += 256) sW3[i] = c3w[i];
    __syncthreads();

    const float4* __restrict__ W2v = (const float4*)sW2;
    const float4* __restrict__ W3v = (const float4*)sW3;

    float vmax[64];
#pragma unroll
    for (int c = 0; c < 64; c++) vmax[c] = 0.0f;   // ReLU outputs >= 0

    const int stride = gridDim.x * blockDim.x;
#pragma unroll 1
    for (int p = blockIdx.x * blockDim.x + t; p < N; p += stride) {
        float px = x[3 + p];
        float py = x[3 + N + p];

        float h1[16];
#pragma unroll
        for (int c = 0; c < 16; c++)
            h1[c] = fmaxf(fmaf(sW1[2 * c], px, fmaf(sW1[2 * c + 1], py, sB1[c])), 0.0f);

        float h2[32];
#pragma unroll 2
        for (int c = 0; c < 32; c++) {
            float a = sB2[c];
#pragma unroll
            for (int q = 0; q < 4; q++) {
                float4 w = W2v[c * 4 + q];
                a = fmaf(w.x, h1[4 * q],
                    fmaf(w.y, h1[4 * q + 1],
                    fmaf(w.z, h1[4 * q + 2],
                    fmaf(w.w, h1[4 * q + 3], a))));
            }
            h2[c] = fmaxf(a, 0.0f);
        }

#pragma unroll 2
        for (int c = 0; c < 64; c++) {
            float a = sB3[c];
#pragma unroll
            for (int q = 0; q < 8; q++) {
                float4 w = W3v[c * 8 + q];
                a = fmaf(w.x, h2[4 * q],
                    fmaf(w.y, h2[4 * q + 1],
                    fmaf(w.z, h2[4 * q + 2],
                    fmaf(w.w, h2[4 * q + 3], a))));
            }
            // relu folded into running max (vmax >= 0 always)
            vmax[c] = fmaxf(vmax[c], a);
        }
    }

    // wave butterfly (64 lanes)
#pragma unroll
    for (int c = 0; c < 64; c++) {
        float v = vmax[c];
#pragma unroll
        for (int off = 32; off > 0; off >>= 1)
            v = fmaxf(v, __shfl_xor(v, off, 64));
        vmax[c] = v;
    }

    int wid = t >> 6, lane = t & 63;
    if (lane == 0) {
#pragma unroll
        for (int c = 0; c < 64; c++) wred[wid * 64 + c] = vmax[c];
    }
    __syncthreads();
    if (t < 64) {
        float m = fmaxf(fmaxf(wred[t], wred[64 + t]),
                        fmaxf(wred[128 + t], wred[192 + t]));
        if (use_atomic)
            atomicMax((unsigned int*)ws + t, __float_as_uint(m)); // valid: m >= 0
        else
            ws[blockIdx.x * 64 + t] = m;
    }
}

// ---------- tail: feat reduce + everything after, one 1024-thread block ----------
__global__ __launch_bounds__(1024) void tail_kernel(
    const float* __restrict__ x,
    const float* __restrict__ hx,  const float* __restrict__ cx,
    const float* __restrict__ fcw, const float* __restrict__ fcb,
    const float* __restrict__ o1w, const float* __restrict__ o1b,
    const float* __restrict__ o2w, const float* __restrict__ o2b,
    const float* __restrict__ pw,  const float* __restrict__ pb,
    const float* __restrict__ wih, const float* __restrict__ whh,
    const float* __restrict__ bih, const float* __restrict__ bhh,
    const float* __restrict__ q1w, const float* __restrict__ q1b,
    const float* __restrict__ q2w, const float* __restrict__ q2b,
    const float* __restrict__ aw1, const float* __restrict__ ab1,
    const float* __restrict__ aw2, const float* __restrict__ ab2,
    const float* __restrict__ ciw1, const float* __restrict__ cib1,
    const float* __restrict__ ciw2, const float* __restrict__ cib2,
    const float* __restrict__ cew1, const float* __restrict__ ceb1,
    const float* __restrict__ cew2, const float* __restrict__ ceb2,
    const float* __restrict__ ws, int nb, int use_atomic,
    float* __restrict__ out)
{
    __shared__ float feat[64], obs[64], sig8[8], pose[8], z[128], hnew[128];
    __shared__ float zp1s[64], zp2s[64], a1s[16], cih[16], ceh[16], logits[5];
    __shared__ float odom[3], wred2[256], gpart[1024], shx[128];
    int t = threadIdx.x;

    if (t < 3)   odom[t] = x[t];
    if (t < 128) shx[t] = hx[t];
    // reduce per-block partials (or read atomic gmax)
    if (t < 256) {
        int c = t & 63, g = t >> 6;
        float m = 0.0f;
        if (use_atomic) {
            if (g == 0) m = __uint_as_float(((const unsigned int*)ws)[c]);
        } else {
            for (int i = g; i < nb; i += 4) m = fmaxf(m, ws[i * 64 + c]);
        }
        wred2[t] = m;
    }
    __syncthreads();
    if (t < 64)
        feat[t] = fmaxf(fmaxf(wred2[t], wred2[64 + t]),
                        fmaxf(wred2[128 + t], wred2[192 + t]));
    __syncthreads();

    if (t < 64) {                       // obs = fcw @ feat + fcb
        float a = fcb[t];
        for (int k = 0; k < 64; k++) a = fmaf(fcw[t * 64 + k], feat[k], a);
        obs[t] = a;
    } else if (t < 72) {                // sig8 = sigmoid(o1w @ odom + o1b)
        int r = t - 64;
        float a = o1b[r];
        for (int k = 0; k < 3; k++) a = fmaf(o1w[r * 3 + k], odom[k], a);
        sig8[r] = 1.0f / (1.0f + expf(-a));
    }
    __syncthreads();

    if (t < 8) {                        // pose = relu(o2w @ sig8 + o2b)
        float a = o2b[t];
        for (int k = 0; k < 8; k++) a = fmaf(o2w[t * 8 + k], sig8[k], a);
        pose[t] = fmaxf(a, 0.0f);
    }
    __syncthreads();

    if (t < 128) {                      // z = relu(pw @ [obs;pose] + pb)
        float a = pb[t];
        for (int k = 0; k < 64; k++) a = fmaf(pw[t * 72 + k], obs[k], a);
        for (int k = 0; k < 8; k++)  a = fmaf(pw[t * 72 + 64 + k], pose[k], a);
        z[t] = fmaxf(a, 0.0f);
    }
    __syncthreads();

    // LSTM gate partials: t<512 -> wih row t against z; t>=512 -> whh row vs shx
    {
        int r = t & 511, half = t >> 9;
        float a;
        if (half == 0) {
            a = bih[r];
            const float4* w4 = (const float4*)(wih + (size_t)r * 128);
#pragma unroll 4
            for (int q = 0; q < 32; q++) {
                float4 w = w4[q];
                a = fmaf(w.x, z[4 * q], fmaf(w.y, z[4 * q + 1],
                    fmaf(w.z, z[4 * q + 2], fmaf(w.w, z[4 * q + 3], a))));
            }
        } else {
            a = bhh[r];
            const float4* w4 = (const float4*)(whh + (size_t)r * 128);
#pragma unroll 4
            for (int q = 0; q < 32; q++) {
                float4 w = w4[q];
                a = fmaf(w.x, shx[4 * q], fmaf(w.y, shx[4 * q + 1],
                    fmaf(w.z, shx[4 * q + 2], fmaf(w.w, shx[4 * q + 3], a))));
            }
        }
        gpart[t] = a;
    }
    __syncthreads();

    if (t < 128) {                      // LSTM cell update
        float gI = gpart[t]       + gpart[512 + t];
        float gF = gpart[128 + t] + gpart[640 + t];
        float gG = gpart[256 + t] + gpart[768 + t];
        float gO = gpart[384 + t] + gpart[896 + t];
        float ig = 1.0f / (1.0f + expf(-gI));
        float fg = 1.0f / (1.0f + expf(-gF));
        float gg = tanhf(gG);
        float og = 1.0f / (1.0f + expf(-gO));
        float cn = fg * cx[t] + ig * gg;
        float hn = og * tanhf(cn);
        hnew[t] = hn;
        out[7 + t]   = hn;              // hx2
        out[135 + t] = cn;              // cx2
    }
    __syncthreads();

    if (t < 64) {                       // zp1 = relu(q1w @ h_new + q1b)
        float a = q1b[t];
        const float4* w4 = (const float4*)(q1w + (size_t)t * 128);
#pragma unroll 4
        for (int q = 0; q < 32; q++) {
            float4 w = w4[q];
            a = fmaf(w.x, hnew[4 * q], fmaf(w.y, hnew[4 * q + 1],
                fmaf(w.z, hnew[4 * q + 2], fmaf(w.w, hnew[4 * q + 3], a))));
        }
        zp1s[t] = fmaxf(a, 0.0f);
    }
    __syncthreads();

    if (t < 64) {                       // zp2 = relu(q2w @ zp1 + q2b)
        float a = q2b[t];
        for (int k = 0; k < 64; k++) a = fmaf(q2w[t * 64 + k], zp1s[k], a);
        zp2s[t] = fmaxf(a, 0.0f);
    }
    __syncthreads();

    if (t < 16) {
        float a = ab1[t];
        for (int k = 0; k < 64; k++) a = fmaf(aw1[t * 64 + k], zp2s[k], a);
        a1s[t] = fmaxf(a, 0.0f);
    } else if (t < 32) {
        int r = t - 16;
        float a = cib1[r];
        for (int k = 0; k < 64; k++) a = fmaf(ciw1[r * 64 + k], zp2s[k], a);
        cih[r] = fmaxf(a, 0.0f);
    } else if (t < 48) {
        int r = t - 32;
        float a = ceb1[r];
        for (int k = 0; k < 64; k++) a = fmaf(cew1[r * 64 + k], zp2s[k], a);
        ceh[r] = fmaxf(a, 0.0f);
    }
    __syncthreads();

    if (t < 5) {
        float a = ab2[t];
        for (int k = 0; k < 16; k++) a = fmaf(aw2[t * 16 + k], a1s[k], a);
        logits[t] = a;
    } else if (t == 5) {                // ci
        float a = cib2[0];
        for (int k = 0; k < 16; k++) a = fmaf(ciw2[k], cih[k], a);
        out[5] = a;
    } else if (t == 6) {                // ce
        float a = ceb2[0];
        for (int k = 0; k < 16; k++) a = fmaf(cew2[k], ceh[k], a);
        out[6] = a;
    }
    if (t >= 8 && t < 16) out[263 + (t - 8)] = pose[t - 8];  // pose
    __syncthreads();

    if (t == 0) {                       // softmax over 5 logits
        float m = logits[0];
        for (int i = 1; i < 5; i++) m = fmaxf(m, logits[i]);
        float e[5], s = 0.0f;
        for (int i = 0; i < 5; i++) { e[i] = expf(logits[i] - m); s += e[i]; }
        for (int i = 0; i < 5; i++) out[i] = e[i] / s;
    }
}

extern "C" void kernel_launch(void* const* d_in, const int* in_sizes, int n_in,
                              void* d_out, int out_size, void* d_ws, size_t ws_size,
                              hipStream_t stream)
{
    const float* x    = (const float*)d_in[0];
    const float* hx   = (const float*)d_in[1];
    const float* cx   = (const float*)d_in[2];
    const float* c1w  = (const float*)d_in[3];
    const float* c1b  = (const float*)d_in[4];
    const float* c2w  = (const float*)d_in[5];
    const float* c2b  = (const float*)d_in[6];
    const float* c3w  = (const float*)d_in[7];
    const float* c3b  = (const float*)d_in[8];
    const float* fcw  = (const float*)d_in[9];
    const float* fcb  = (const float*)d_in[10];
    const float* o1w  = (const float*)d_in[11];
    const float* o1b  = (const float*)d_in[12];
    const float* o2w  = (const float*)d_in[13];
    const float* o2b  = (const float*)d_in[14];
    const float* pw   = (const float*)d_in[15];
    const float* pb   = (const float*)d_in[16];
    const float* wih  = (const float*)d_in[17];
    const float* whh  = (const float*)d_in[18];
    const float* bih  = (const float*)d_in[19];
    const float* bhh  = (const float*)d_in[20];
    const float* q1w  = (const float*)d_in[21];
    const float* q1b  = (const float*)d_in[22];
    const float* q2w  = (const float*)d_in[23];
    const float* q2b  = (const float*)d_in[24];
    const float* aw1  = (const float*)d_in[25];
    const float* ab1  = (const float*)d_in[26];
    const float* aw2  = (const float*)d_in[27];
    const float* ab2  = (const float*)d_in[28];
    const float* ciw1 = (const float*)d_in[29];
    const float* cib1 = (const float*)d_in[30];
    const float* ciw2 = (const float*)d_in[31];
    const float* cib2 = (const float*)d_in[32];
    const float* cew1 = (const float*)d_in[33];
    const float* ceb1 = (const float*)d_in[34];
    const float* cew2 = (const float*)d_in[35];
    const float* ceb2 = (const float*)d_in[36];

    int N = (in_sizes[0] - 3) / 2;
    int use_atomic = (ws_size < (size_t)(NB * 64 * 4)) ? 1 : 0;

    if (use_atomic)
        prep_kernel<<<1, 64, 0, stream>>>((unsigned int*)d_ws);
    encoder_kernel<<<NB, 256, 0, stream>>>(x, c1w, c1b, c2w, c2b, c3w, c3b,
                                           (float*)d_ws, N, use_atomic);
    tail_kernel<<<1, 1024, 0, stream>>>(x, hx, cx, fcw, fcb, o1w, o1b, o2w, o2b,
                                        pw, pb, wih, whh, bih, bhh, q1w, q1b,
                                        q2w, q2b, aw1, ab1, aw2, ab2, ciw1, cib1,
                                        ciw2, cib2, cew1, ceb1, cew2, ceb2,
                                        (const float*)d_ws, NB, use_atomic,
                                        (float*)d_out);
}